// Round 4
// baseline (368.557 us; speedup 1.0000x reference)
//
#include <hip/hip_runtime.h>
#include <math.h>

#define DIM 4096
#define NH 32
#define NKV 8
#define HD 128
#define WINDOW 4096
#define BATCH 32
#define QKV_N 6144
#define ATTN_SCALE 0.08838834764831845f
#define WCHUNK 128
#define NCW 32        // WINDOW / WCHUNK
#define SLICES 16     // GEMM K-split

__device__ __forceinline__ float4 f4max(float4 a, float4 b) {
  return make_float4(fmaxf(a.x, b.x), fmaxf(a.y, b.y), fmaxf(a.z, b.z), fmaxf(a.w, b.w));
}
__device__ __forceinline__ float4 f4add(float4 a, float4 b) {
  return make_float4(a.x + b.x, a.y + b.y, a.z + b.z, a.w + b.w);
}
__device__ __forceinline__ void fma4(float4& a, float4 x, float4 y) {
  a.x = fmaf(x.x, y.x, a.x); a.y = fmaf(x.y, y.y, a.y);
  a.z = fmaf(x.z, y.z, a.z); a.w = fmaf(x.w, y.w, a.w);
}
__device__ __forceinline__ void fma4s(float4& a, float s, float4 v) {
  a.x = fmaf(s, v.x, a.x); a.y = fmaf(s, v.y, a.y);
  a.z = fmaf(s, v.z, a.z); a.w = fmaf(s, v.w, a.w);
}
__device__ __forceinline__ float4 wred_max(float4 v) {
#pragma unroll
  for (int o = 1; o < 64; o <<= 1) {
    v.x = fmaxf(v.x, __shfl_xor(v.x, o));
    v.y = fmaxf(v.y, __shfl_xor(v.y, o));
    v.z = fmaxf(v.z, __shfl_xor(v.z, o));
    v.w = fmaxf(v.w, __shfl_xor(v.w, o));
  }
  return v;
}
__device__ __forceinline__ float4 wred_add(float4 v) {
#pragma unroll
  for (int o = 1; o < 64; o <<= 1) {
    v.x += __shfl_xor(v.x, o);
    v.y += __shfl_xor(v.y, o);
    v.z += __shfl_xor(v.z, o);
    v.w += __shfl_xor(v.w, o);
  }
  return v;
}
__device__ __forceinline__ void xor32_add(float4& v) {
  v.x += __shfl_xor(v.x, 32);
  v.y += __shfl_xor(v.y, 32);
  v.z += __shfl_xor(v.z, 32);
  v.w += __shfl_xor(v.w, 32);
}

// ---------------------------------------------------------------------------
// GEMM partials: part[(slice*32 + r)*N + c] = sum_{k in slice} x[r][k]*w[k][c]
// grid = (N/64, NS). block = 256. thread: 4 cols (float4 of w), 2 rows.
// ---------------------------------------------------------------------------
template<int N, int K, int NS>
__global__ __launch_bounds__(256)
void gemm_part(const float* __restrict__ x, const float* __restrict__ w,
               float* __restrict__ part) {
  const int t = threadIdx.x;
  const int c0 = blockIdx.x * 64 + (t & 15) * 4;
  const int r0 = (t >> 4) * 2;
  const int kn = K / NS;
  const int ks = blockIdx.y * kn;

  float a00 = 0.f, a01 = 0.f, a02 = 0.f, a03 = 0.f;
  float a10 = 0.f, a11 = 0.f, a12 = 0.f, a13 = 0.f;

  const float* xr0 = x + (size_t)r0 * K;
  const float* xr1 = xr0 + K;
  const float* wp = w + (size_t)ks * N + c0;

  for (int k = ks; k < ks + kn; k += 4) {
    float4 xa = *(const float4*)(xr0 + k);
    float4 xb = *(const float4*)(xr1 + k);
    float xav[4] = {xa.x, xa.y, xa.z, xa.w};
    float xbv[4] = {xb.x, xb.y, xb.z, xb.w};
#pragma unroll
    for (int kk = 0; kk < 4; ++kk) {
      float4 wv = *(const float4*)(wp);
      wp += N;
      a00 = fmaf(xav[kk], wv.x, a00);
      a01 = fmaf(xav[kk], wv.y, a01);
      a02 = fmaf(xav[kk], wv.z, a02);
      a03 = fmaf(xav[kk], wv.w, a03);
      a10 = fmaf(xbv[kk], wv.x, a10);
      a11 = fmaf(xbv[kk], wv.y, a11);
      a12 = fmaf(xbv[kk], wv.z, a12);
      a13 = fmaf(xbv[kk], wv.w, a13);
    }
  }
  float* p = part + ((size_t)blockIdx.y * 32 + r0) * N + c0;
  *(float4*)p = make_float4(a00, a01, a02, a03);
  *(float4*)(p + N) = make_float4(a10, a11, a12, a13);
}

// ---------------------------------------------------------------------------
// Reduce the SLICES K-slices of the qkv GEMM, apply RoPE, scatter q/knew/vnew.
// ---------------------------------------------------------------------------
__global__ __launch_bounds__(256)
void rope_reduce(const float* __restrict__ part, const float* __restrict__ cosv,
                 const float* __restrict__ sinv, float* __restrict__ q,
                 float* __restrict__ knew, float* __restrict__ vnew) {
  int idx = blockIdx.x * 256 + threadIdx.x;   // < 32*48*64 = 98304
  int r = idx / 3072;
  int rem = idx - r * 3072;
  int head = rem >> 6;     // 0..47  (0..31 q, 32..39 k, 40..47 v)
  int d = rem & 63;
  int c1 = head * 128 + d;
  int c2 = c1 + 64;
  float v1 = 0.f, v2 = 0.f;
#pragma unroll
  for (int s = 0; s < SLICES; ++s) {
    v1 += part[((size_t)s * 32 + r) * QKV_N + c1];
    v2 += part[((size_t)s * 32 + r) * QKV_N + c2];
  }
  if (head < NH + NKV) {
    float c_lo = cosv[d], c_hi = cosv[d + 64];
    float s_lo = sinv[d], s_hi = sinv[d + 64];
    float o1 = v1 * c_lo - v2 * s_lo;
    float o2 = v2 * c_hi + v1 * s_hi;
    if (head < NH) {
      q[((size_t)r * NH + head) * HD + d] = o1;
      q[((size_t)r * NH + head) * HD + d + 64] = o2;
    } else {
      int g = head - NH;
      knew[((size_t)r * NKV + g) * HD + d] = o1;
      knew[((size_t)r * NKV + g) * HD + d + 64] = o2;
    }
  } else {
    int g = head - NH - NKV;
    vnew[((size_t)r * NKV + g) * HD + d] = v1;
    vnew[((size_t)r * NKV + g) * HD + d + 64] = v2;
  }
}

// ---------------------------------------------------------------------------
// Barrier-free flash-decode: each WAVE owns one 128-position chunk.
// Block = 4 waves, each with private LDS slices (q + scores). No __syncthreads.
// grid (256 bg, NCW/4). Emits pvp[c][bg][h][d] and msp[c][bg][h][{m,s}].
// ---------------------------------------------------------------------------
__global__ __launch_bounds__(256, 5)
void attn_wave(const float* __restrict__ q, const float* __restrict__ knew,
               const float* __restrict__ vnew, const float* __restrict__ cache_k,
               const float* __restrict__ cache_v, const float* __restrict__ mask,
               const int* __restrict__ start_pos_p,
               float* __restrict__ pvp, float* __restrict__ msp) {
  const int bg = blockIdx.x;            // b*NKV + g
  const int b = bg >> 3;
  const int w = threadIdx.x >> 6;       // wave 0..3
  const int lane = threadIdx.x & 63;
  const int c = blockIdx.y * 4 + w;     // chunk 0..31
  const int sp = start_pos_p[0];
  const int cur = sp & (WINDOW - 1);
  int plen = ((sp + 1 + 31) >> 5) << 5;
  if (plen > WINDOW) plen = WINDOW;
  const int t0 = c * WCHUNK;
  const int tend = min(t0 + WCHUNK, plen);

  const size_t pidx = ((size_t)c * 256 + bg) * 4;
  float* pvb = pvp + pidx * HD;
  float* msb = msp + pidx * 2;

  __shared__ __align__(16) float q_s[4][4 * HD];       // per-wave, 8 KB total
  __shared__ __align__(16) float s_s[4][WCHUNK][4];    // per-wave, 8 KB total

  if (t0 >= plen) {   // inactive chunk: neutral partials (wave-scoped)
    if (lane < 8) msb[lane] = (lane & 1) ? 0.f : -1e30f;
    for (int i = lane; i < 4 * HD; i += 64) pvb[i] = 0.f;
    return;
  }

  // wave-local q load (4 heads x 128, contiguous 512 floats) — no barrier
  {
    const float* qsrc = q + ((size_t)b * NH + (bg & 7) * 4) * HD;
    float4 v0 = *(const float4*)(qsrc + lane * 8);
    float4 v1 = *(const float4*)(qsrc + lane * 8 + 4);
    *(float4*)(&q_s[w][lane * 8]) = v0;
    *(float4*)(&q_s[w][lane * 8 + 4]) = v1;
  }

  const float* kbase = cache_k + (size_t)bg * WINDOW * HD;
  const float* vbase = cache_v + (size_t)bg * WINDOW * HD;
  const float* krow_new = knew + (size_t)bg * HD;
  const float* vrow_new = vnew + (size_t)bg * HD;

  // ---- Phase 1: scores into this wave's LDS slice ----
  {
    const int p0 = lane >> 2;   // 0..15
    const int dl = lane & 3;
    for (int tt = t0 + p0; tt < t0 + WCHUNK; tt += 16) {
      if (tt < tend) {
        const float* krow = (tt == cur) ? krow_new : (kbase + (size_t)tt * HD);
        float4 a0 = {0,0,0,0}, a1 = {0,0,0,0}, a2 = {0,0,0,0}, a3 = {0,0,0,0};
#pragma unroll
        for (int j = 0; j < 8; ++j) {
          const int f = dl + 4 * j;
          float4 kv = *(const float4*)(krow + 4 * f);
          fma4(a0, kv, *(const float4*)(&q_s[w][0 * HD + 4 * f]));
          fma4(a1, kv, *(const float4*)(&q_s[w][1 * HD + 4 * f]));
          fma4(a2, kv, *(const float4*)(&q_s[w][2 * HD + 4 * f]));
          fma4(a3, kv, *(const float4*)(&q_s[w][3 * HD + 4 * f]));
        }
        float s0 = a0.x + a0.y + a0.z + a0.w;
        float s1 = a1.x + a1.y + a1.z + a1.w;
        float s2 = a2.x + a2.y + a2.z + a2.w;
        float s3 = a3.x + a3.y + a3.z + a3.w;
        s0 += __shfl_xor(s0, 1); s0 += __shfl_xor(s0, 2);
        s1 += __shfl_xor(s1, 1); s1 += __shfl_xor(s1, 2);
        s2 += __shfl_xor(s2, 1); s2 += __shfl_xor(s2, 2);
        s3 += __shfl_xor(s3, 1); s3 += __shfl_xor(s3, 2);
        float sv = (dl == 0) ? s0 : (dl == 1) ? s1 : (dl == 2) ? s2 : s3;
        s_s[w][tt - t0][dl] = sv * ATTN_SCALE + mask[(size_t)b * WINDOW + tt];
      } else {
        s_s[w][tt - t0][dl] = -1e30f;
      }
    }
  }
  // wave-coherent LDS: compiler inserts lgkmcnt waits; no barrier needed

  // ---- Phase 2: softmax over this wave's 128 rows ----
  float4 r0 = *(const float4*)(s_s[w][lane]);
  float4 r1 = *(const float4*)(s_s[w][lane + 64]);
  float4 mx = wred_max(f4max(r0, r1));
  float4 e0, e1;
  e0.x = __expf(r0.x - mx.x); e0.y = __expf(r0.y - mx.y);
  e0.z = __expf(r0.z - mx.z); e0.w = __expf(r0.w - mx.w);
  e1.x = __expf(r1.x - mx.x); e1.y = __expf(r1.y - mx.y);
  e1.z = __expf(r1.z - mx.z); e1.w = __expf(r1.w - mx.w);
  *(float4*)(s_s[w][lane]) = e0;
  *(float4*)(s_s[w][lane + 64]) = e1;
  float4 sm = wred_add(f4add(e0, e1));
  if (lane == 0) {
    msb[0] = mx.x; msb[1] = sm.x;
    msb[2] = mx.y; msb[3] = sm.y;
    msb[4] = mx.z; msb[5] = sm.z;
    msb[6] = mx.w; msb[7] = sm.w;
  }

  // ---- Phase 3: PV over this wave's chunk ----
  {
    const int d4 = lane & 31;    // float4 index over 128 dims
    const int half = lane >> 5;  // 0..1
    float4 a0 = {0,0,0,0}, a1 = {0,0,0,0}, a2 = {0,0,0,0}, a3 = {0,0,0,0};
    for (int tt = t0 + half; tt < tend; tt += 2) {
      const float* vrow = (tt == cur) ? vrow_new : (vbase + (size_t)tt * HD);
      float4 vv = *(const float4*)(vrow + 4 * d4);
      float4 p = *(const float4*)(s_s[w][tt - t0]);   // broadcast within half-wave
      fma4s(a0, p.x, vv);
      fma4s(a1, p.y, vv);
      fma4s(a2, p.z, vv);
      fma4s(a3, p.w, vv);
    }
    xor32_add(a0); xor32_add(a1); xor32_add(a2); xor32_add(a3);
    if (half == 0) {
      *(float4*)(&pvb[0 * HD + 4 * d4]) = a0;
      *(float4*)(&pvb[1 * HD + 4 * d4]) = a1;
      *(float4*)(&pvb[2 * HD + 4 * d4]) = a2;
      *(float4*)(&pvb[3 * HD + 4 * d4]) = a3;
    }
  }
}

// ---------------------------------------------------------------------------
// Combine chunk partials: online LSE merge over NCW chunks (no reg arrays).
// ---------------------------------------------------------------------------
__global__ __launch_bounds__(256)
void attn_combine(const float* __restrict__ pvp, const float* __restrict__ msp,
                  float* __restrict__ attn_out) {
  int idx = blockIdx.x * 256 + threadIdx.x;   // < 32*4096
  int b = idx >> 12;
  int rem = idx & 4095;
  int hf = rem >> 7;    // 0..31
  int d = rem & 127;
  int g = hf >> 2, hh = hf & 3;
  int bg = b * 8 + g;
  float M = -1e30f, den = 0.f, num = 0.f;
#pragma unroll 4
  for (int c = 0; c < NCW; ++c) {
    size_t base = ((size_t)c * 256 + bg) * 4 + hh;
    float m = msp[base * 2];
    float s = msp[base * 2 + 1];
    float p = pvp[base * HD + d];
    float Mn = fmaxf(M, m);
    float so = __expf(M - Mn);
    float sn = __expf(m - Mn);
    den = den * so + s * sn;
    num = num * so + p * sn;
    M = Mn;
  }
  attn_out[idx] = num / den;
}

// ---------------------------------------------------------------------------
// Final reduce of wo GEMM partials -> d_out
// ---------------------------------------------------------------------------
__global__ __launch_bounds__(256)
void reduce_out(const float* __restrict__ part, float* __restrict__ out) {
  int idx = blockIdx.x * 256 + threadIdx.x;   // < 32*4096
  float s = 0.f;
#pragma unroll
  for (int sl = 0; sl < SLICES; ++sl) s += part[(size_t)sl * 32 * DIM + idx];
  out[idx] = s;
}

extern "C" void kernel_launch(void* const* d_in, const int* in_sizes, int n_in,
                              void* d_out, int out_size, void* d_ws, size_t ws_size,
                              hipStream_t stream) {
  const float* x       = (const float*)d_in[0];
  const float* wqkv    = (const float*)d_in[1];
  const float* wo      = (const float*)d_in[2];
  const float* cosv    = (const float*)d_in[3];
  const float* sinv    = (const float*)d_in[4];
  const float* cache_k = (const float*)d_in[5];
  const float* cache_v = (const float*)d_in[6];
  const float* mask    = (const float*)d_in[7];
  const int*   start_p = (const int*)d_in[8];
  float* ws = (float*)d_ws;

  float* part     = ws;                      // SLICES*32*6144 = 3,145,728 floats
  float* q        = ws + 3145728;            // 131072
  float* knew     = q + 131072;              // 32768
  float* vnew     = knew + 32768;            // 32768
  float* attn_out = vnew + 32768;            // 131072
  float* pvp      = attn_out + 131072;       // NCW*256*4*128 = 4,194,304
  float* msp      = pvp + 4194304;           // NCW*256*4*2 = 65536
  float* out      = (float*)d_out;

  gemm_part<QKV_N, DIM, SLICES><<<dim3(QKV_N / 64, SLICES), 256, 0, stream>>>(x, wqkv, part);
  rope_reduce<<<384, 256, 0, stream>>>(part, cosv, sinv, q, knew, vnew);
  attn_wave<<<dim3(BATCH * NKV, NCW / 4), 256, 0, stream>>>(q, knew, vnew, cache_k,
                                                            cache_v, mask, start_p,
                                                            pvp, msp);
  attn_combine<<<512, 256, 0, stream>>>(pvp, msp, attn_out);
  gemm_part<DIM, DIM, SLICES><<<dim3(DIM / 64, SLICES), 256, 0, stream>>>(attn_out, wo, part);
  reduce_out<<<512, 256, 0, stream>>>(part, out);
}